// Round 1
// baseline (586.055 us; speedup 1.0000x reference)
//
#include <hip/hip_runtime.h>
#include <hip/hip_bf16.h>

typedef __bf16 bf16x8 __attribute__((ext_vector_type(8)));
typedef __bf16 bf16x4 __attribute__((ext_vector_type(4)));
typedef float  f32x4  __attribute__((ext_vector_type(4)));

#define MFMA(a, b, c) __builtin_amdgcn_mfma_f32_16x16x32_bf16((a), (b), (c), 0, 0, 0)

// ---------------------------------------------------------------------------
// Weight transpose + f32->bf16 convert:  src f32 [K][N]  ->  dst bf16 [N][K]
// ---------------------------------------------------------------------------
__global__ __launch_bounds__(256) void transpose_cvt(
    const float* __restrict__ src, __bf16* __restrict__ dst, int Kd, int Nd)
{
    __shared__ float tile[32][33];
    const int k0 = blockIdx.y * 32, n0 = blockIdx.x * 32;
    const int t = threadIdx.x;
    const int r = t >> 5, c = t & 31;
#pragma unroll
    for (int i = 0; i < 4; ++i)
        tile[r + i * 8][c] = src[(long)(k0 + r + i * 8) * Nd + n0 + c];
    __syncthreads();
#pragma unroll
    for (int i = 0; i < 4; ++i)
        dst[(long)(n0 + r + i * 8) * Kd + k0 + c] = (__bf16)tile[c][r + i * 8];
}

// ---------------------------------------------------------------------------
// LayerNorm (torch semantics: ddof=1 std, eps added to std), f32 in, bf16 out
// One block (256 threads) per row of 1024.
// ---------------------------------------------------------------------------
__global__ __launch_bounds__(256) void ln_kernel(
    const float* __restrict__ in, const float* __restrict__ ga,
    const float* __restrict__ gb, __bf16* __restrict__ out)
{
    const int row = blockIdx.x;
    const int t = threadIdx.x;
    const float4 xv = *(const float4*)(in + (long)row * 1024 + t * 4);
    float s  = xv.x + xv.y + xv.z + xv.w;
    float sq = xv.x * xv.x + xv.y * xv.y + xv.z * xv.z + xv.w * xv.w;
#pragma unroll
    for (int off = 32; off; off >>= 1) {
        s  += __shfl_xor(s, off);
        sq += __shfl_xor(sq, off);
    }
    __shared__ float red[8];
    const int w = t >> 6;
    if ((t & 63) == 0) { red[w * 2] = s; red[w * 2 + 1] = sq; }
    __syncthreads();
    s  = red[0] + red[2] + red[4] + red[6];
    sq = red[1] + red[3] + red[5] + red[7];
    const float mean = s * (1.0f / 1024.0f);
    const float var  = fmaxf((sq - s * mean) * (1.0f / 1023.0f), 0.0f);
    const float dinv = 1.0f / (sqrtf(var) + 1e-6f);
    const float4 av = *(const float4*)(ga + t * 4);
    const float4 bv = *(const float4*)(gb + t * 4);
    bf16x4 o;
    o[0] = (__bf16)((xv.x - mean) * dinv * av.x + bv.x);
    o[1] = (__bf16)((xv.y - mean) * dinv * av.y + bv.y);
    o[2] = (__bf16)((xv.z - mean) * dinv * av.z + bv.z);
    o[3] = (__bf16)((xv.w - mean) * dinv * av.w + bv.w);
    *(bf16x4*)(out + (long)row * 1024 + t * 4) = o;
}

// ---------------------------------------------------------------------------
// GEMM: C[M,N] = A[M,K] @ B[K,N], with B given transposed (Bt[N][K], bf16).
// 128x128 tile, BK=32, 4 waves, each wave 64x64 (4x4 of 16x16x32 MFMA frags).
// MODE 0: QKV -> scatter to Q/K/V [B,H,S,dk] bf16
// MODE 1: + resid (f32) -> f32 out
// MODE 2: + bias, ReLU -> bf16 out
// MODE 3: + bias + resid (f32, may alias out) -> f32 out
// ---------------------------------------------------------------------------
template <int MODE>
__global__ __launch_bounds__(256) void gemm_bt(
    const __bf16* __restrict__ A, const __bf16* __restrict__ Bt,
    int M, int N, int K,
    const float* __restrict__ bias, const float* resid,
    float* outf, __bf16* __restrict__ outb,
    __bf16* __restrict__ qb, __bf16* __restrict__ kb, __bf16* __restrict__ vb)
{
    __shared__ __align__(16) __bf16 Alds[128 * 32];
    __shared__ __align__(16) __bf16 Blds[128 * 32];

    const int t = threadIdx.x;
    const int lane = t & 63, w = t >> 6;
    const int wr = w >> 1, wc = w & 1;
    const int g = lane >> 4, l15 = lane & 15;
    const int bm = blockIdx.y * 128, bn = blockIdx.x * 128;

    // staging: 512 chunks of 16B per tile; this thread handles chunks t, t+256
    const int m0 = t >> 2;                 // 0..63
    const int ko = (t & 3) * 8;            // 0,8,16,24
    const int m1 = m0 + 64;

    const __bf16* Ag = A  + (long)bm * K;
    const __bf16* Bg = Bt + (long)bn * K;

    f32x4 acc[4][4] = {};
    const int nk = K / 32;

    bf16x8 ra0 = *(const bf16x8*)(Ag + (long)m0 * K + ko);
    bf16x8 ra1 = *(const bf16x8*)(Ag + (long)m1 * K + ko);
    bf16x8 rb0 = *(const bf16x8*)(Bg + (long)m0 * K + ko);
    bf16x8 rb1 = *(const bf16x8*)(Bg + (long)m1 * K + ko);

    for (int kt = 0; kt < nk; ++kt) {
        __syncthreads();
        *(bf16x8*)(Alds + m0 * 32 + ko) = ra0;
        *(bf16x8*)(Alds + m1 * 32 + ko) = ra1;
        *(bf16x8*)(Blds + m0 * 32 + ko) = rb0;
        *(bf16x8*)(Blds + m1 * 32 + ko) = rb1;
        __syncthreads();
        if (kt + 1 < nk) {
            const int kg = (kt + 1) * 32 + ko;
            ra0 = *(const bf16x8*)(Ag + (long)m0 * K + kg);
            ra1 = *(const bf16x8*)(Ag + (long)m1 * K + kg);
            rb0 = *(const bf16x8*)(Bg + (long)m0 * K + kg);
            rb1 = *(const bf16x8*)(Bg + (long)m1 * K + kg);
        }
        bf16x8 af[4], bfr[4];
#pragma unroll
        for (int mi = 0; mi < 4; ++mi)
            af[mi] = *(const bf16x8*)(Alds + (wr * 64 + mi * 16 + l15) * 32 + g * 8);
#pragma unroll
        for (int ni = 0; ni < 4; ++ni)
            bfr[ni] = *(const bf16x8*)(Blds + (wc * 64 + ni * 16 + l15) * 32 + g * 8);
#pragma unroll
        for (int mi = 0; mi < 4; ++mi)
#pragma unroll
            for (int ni = 0; ni < 4; ++ni)
                acc[mi][ni] = MFMA(af[mi], bfr[ni], acc[mi][ni]);
    }

    // epilogue: C/D layout col = lane&15, row = (lane>>4)*4 + reg  [verified]
#pragma unroll
    for (int mi = 0; mi < 4; ++mi) {
#pragma unroll
        for (int ni = 0; ni < 4; ++ni) {
#pragma unroll
            for (int r = 0; r < 4; ++r) {
                const int gr = bm + wr * 64 + mi * 16 + g * 4 + r;
                const int gc = bn + wc * 64 + ni * 16 + l15;
                const float vacc = acc[mi][ni][r];
                if constexpr (MODE == 0) {
                    const int bufi = gc >> 10;
                    const int hd = gc & 1023;
                    const int h = hd >> 6, d = hd & 63;
                    const int b = gr >> 11, sx = gr & 2047;
                    __bf16* dst = (bufi == 0) ? qb : ((bufi == 1) ? kb : vb);
                    dst[((long)((b * 16 + h) * 2048 + sx)) * 64 + d] = (__bf16)vacc;
                } else if constexpr (MODE == 1) {
                    const long idx = (long)gr * N + gc;
                    outf[idx] = vacc + resid[idx];
                } else if constexpr (MODE == 2) {
                    const float y = fmaxf(vacc + bias[gc], 0.0f);
                    outb[(long)gr * N + gc] = (__bf16)y;
                } else {
                    const long idx = (long)gr * N + gc;
                    outf[idx] = vacc + bias[gc] + resid[idx];
                }
            }
        }
    }
}

// ---------------------------------------------------------------------------
// Flash attention, swapped QK^T: per wave 16 q-rows, kv-chunks of 32.
// S^T = K_chunk . Q^T via MFMA -> lane owns P[kv...] for q = lane&15.
// O^T = V^T . P^T accumulated; rescale is lane-uniform (col = q = lane&15).
// ---------------------------------------------------------------------------
__global__ __launch_bounds__(256) void attn_kernel(
    const __bf16* __restrict__ Q, const __bf16* __restrict__ Kk,
    const __bf16* __restrict__ V, const int* __restrict__ mask,
    __bf16* __restrict__ O)
{
    __shared__ __align__(16) __bf16 Klds[32 * 64];
    __shared__ __align__(16) __bf16 Vlds[32 * 64];
    __shared__ int mlds[32];

    const int t = threadIdx.x;
    const int lane = t & 63, w = t >> 6;
    const int g = lane >> 4, l15 = lane & 15;
    const int bh = blockIdx.x >> 5;     // b*16+h
    const int qt = blockIdx.x & 31;
    const int b = bh >> 4;
    const int q0 = qt * 64 + w * 16;

    const __bf16* Qp = Q  + (long)bh * 2048 * 64;
    const __bf16* Kp = Kk + (long)bh * 2048 * 64;
    const __bf16* Vp = V  + (long)bh * 2048 * 64;

    bf16x8 qreg0 = *(const bf16x8*)(Qp + (long)(q0 + l15) * 64 + g * 8);
    bf16x8 qreg1 = *(const bf16x8*)(Qp + (long)(q0 + l15) * 64 + 32 + g * 8);

    float m_run = -1e30f, l_run = 0.0f;
    f32x4 ot[4] = {};

    const int srow = t >> 3;            // 0..31
    const int sko = (t & 7) * 8;        // 0..56

    for (int kc = 0; kc < 64; ++kc) {
        const int kv0 = kc * 32;
        __syncthreads();
        *(bf16x8*)(Klds + srow * 64 + sko) = *(const bf16x8*)(Kp + (long)(kv0 + srow) * 64 + sko);
        *(bf16x8*)(Vlds + srow * 64 + sko) = *(const bf16x8*)(Vp + (long)(kv0 + srow) * 64 + sko);
        if (t < 32) mlds[t] = mask[b * 2048 + kv0 + t];
        __syncthreads();

        f32x4 sf0 = {}, sf1 = {};
        {
            bf16x8 a0 = *(const bf16x8*)(Klds + l15 * 64 + g * 8);
            bf16x8 a1 = *(const bf16x8*)(Klds + l15 * 64 + 32 + g * 8);
            sf0 = MFMA(a0, qreg0, sf0);
            sf0 = MFMA(a1, qreg1, sf0);
            bf16x8 c0 = *(const bf16x8*)(Klds + (16 + l15) * 64 + g * 8);
            bf16x8 c1 = *(const bf16x8*)(Klds + (16 + l15) * 64 + 32 + g * 8);
            sf1 = MFMA(c0, qreg0, sf1);
            sf1 = MFMA(c1, qreg1, sf1);
        }

        float s[8], p[8];
        float mx = -1e30f;
#pragma unroll
        for (int j = 0; j < 8; ++j) {
            const int fr = j >> 2, r = j & 3;
            float xs = (fr ? sf1[r] : sf0[r]) * 0.125f;
            const int kv = fr * 16 + g * 4 + r;
            if (mlds[kv] == 0) xs = -1e9f;
            s[j] = xs;
            mx = fmaxf(mx, xs);
        }
        mx = fmaxf(mx, __shfl_xor(mx, 16));
        mx = fmaxf(mx, __shfl_xor(mx, 32));
        const float m_new = fmaxf(m_run, mx);
        const float alpha = __expf(m_run - m_new);
        float psum = 0.0f;
#pragma unroll
        for (int j = 0; j < 8; ++j) { p[j] = __expf(s[j] - m_new); psum += p[j]; }
        psum += __shfl_xor(psum, 16);
        psum += __shfl_xor(psum, 32);
        l_run = l_run * alpha + psum;
        m_run = m_new;
#pragma unroll
        for (int df = 0; df < 4; ++df)
#pragma unroll
            for (int r = 0; r < 4; ++r) ot[df][r] *= alpha;

        bf16x8 pb;
#pragma unroll
        for (int j = 0; j < 8; ++j) pb[j] = (__bf16)p[j];   // kv(g,j)=g*4+(j&3)+16*(j>>2)

#pragma unroll
        for (int df = 0; df < 4; ++df) {
            bf16x8 av;
#pragma unroll
            for (int j = 0; j < 8; ++j) {
                const int kv = g * 4 + (j & 3) + 16 * (j >> 2);
                av[j] = Vlds[kv * 64 + df * 16 + l15];
            }
            ot[df] = MFMA(av, pb, ot[df]);
        }
    }

    const float inv = 1.0f / l_run;
    const int h = bh & 15;
    const long orow = (long)(b * 2048 + q0 + l15) * 1024 + h * 64;
#pragma unroll
    for (int df = 0; df < 4; ++df)
#pragma unroll
        for (int r = 0; r < 4; ++r) {
            const int d = df * 16 + g * 4 + r;
            O[orow + d] = (__bf16)(ot[df][r] * inv);
        }
}

// ---------------------------------------------------------------------------
extern "C" void kernel_launch(void* const* d_in, const int* in_sizes, int n_in,
                              void* d_out, int out_size, void* d_ws, size_t ws_size,
                              hipStream_t stream)
{
    const float* x    = (const float*)d_in[0];
    const int*   mask = (const int*)  d_in[1];
    const float* wq   = (const float*)d_in[2];
    const float* wk   = (const float*)d_in[3];
    const float* wv   = (const float*)d_in[4];
    const float* wo   = (const float*)d_in[5];
    const float* w1   = (const float*)d_in[6];
    const float* b1   = (const float*)d_in[7];
    const float* w2   = (const float*)d_in[8];
    const float* b2   = (const float*)d_in[9];
    const float* l1a  = (const float*)d_in[10];
    const float* l1b  = (const float*)d_in[11];
    const float* l2a  = (const float*)d_in[12];
    const float* l2b  = (const float*)d_in[13];
    float* out = (float*)d_out;

    char* ws = (char*)d_ws;
    __bf16* wqkvT = (__bf16*)(ws);                       // [3072][1024]  6 MB
    __bf16* woT   = (__bf16*)(ws + 6291456);             // [1024][1024]  2 MB
    __bf16* w1T   = (__bf16*)(ws + 8388608);             // [4096][1024]  8 MB
    __bf16* w2T   = (__bf16*)(ws + 16777216);            // [1024][4096]  8 MB
    __bf16* xn    = (__bf16*)(ws + 25165824);            // [8192][1024] 16 MB
    __bf16* Qb    = (__bf16*)(ws + 41943040);            // [64][2048][64] 16 MB
    __bf16* Kb    = (__bf16*)(ws + 58720256);            // 16 MB
    __bf16* Vb    = (__bf16*)(ws + 75497472);            // 16 MB
    __bf16* attO  = (__bf16*)(ws + 92274688);            // [8192][1024] 16 MB
    __bf16* ffh   = (__bf16*)(ws + 41943040);            // [8192][4096] 64 MB (reuses Q..attO)

    // weights -> bf16 transposed
    transpose_cvt<<<dim3(32, 32),  256, 0, stream>>>(wq, wqkvT,                 1024, 1024);
    transpose_cvt<<<dim3(32, 32),  256, 0, stream>>>(wk, wqkvT + 1024 * 1024,   1024, 1024);
    transpose_cvt<<<dim3(32, 32),  256, 0, stream>>>(wv, wqkvT + 2048 * 1024,   1024, 1024);
    transpose_cvt<<<dim3(32, 32),  256, 0, stream>>>(wo, woT,                   1024, 1024);
    transpose_cvt<<<dim3(128, 32), 256, 0, stream>>>(w1, w1T,                   1024, 4096);
    transpose_cvt<<<dim3(32, 128), 256, 0, stream>>>(w2, w2T,                   4096, 1024);

    // LN1
    ln_kernel<<<8192, 256, 0, stream>>>(x, l1a, l1b, xn);
    // QKV (fused N=3072), scatter to [B,H,S,dk]
    gemm_bt<0><<<dim3(24, 64), 256, 0, stream>>>(xn, wqkvT, 8192, 3072, 1024,
                                                 nullptr, nullptr, nullptr, nullptr, Qb, Kb, Vb);
    // attention
    attn_kernel<<<2048, 256, 0, stream>>>(Qb, Kb, Vb, mask, attO);
    // WO + residual(x) -> d_out (f32)
    gemm_bt<1><<<dim3(8, 64), 256, 0, stream>>>(attO, woT, 8192, 1024, 1024,
                                                nullptr, x, out, nullptr, nullptr, nullptr, nullptr);
    // LN2
    ln_kernel<<<8192, 256, 0, stream>>>(out, l2a, l2b, xn);
    // FFN1 + bias + ReLU -> bf16
    gemm_bt<2><<<dim3(32, 64), 256, 0, stream>>>(xn, w1T, 8192, 4096, 1024,
                                                 b1, nullptr, nullptr, ffh, nullptr, nullptr, nullptr);
    // FFN2 + bias + residual(d_out) -> d_out
    gemm_bt<3><<<dim3(8, 64), 256, 0, stream>>>(ffh, w2T, 8192, 1024, 4096,
                                                b2, out, out, nullptr, nullptr, nullptr, nullptr);
    (void)in_sizes; (void)n_in; (void)out_size; (void)ws_size;
}

// Round 2
// 532.442 us; speedup vs baseline: 1.1007x; 1.1007x over previous
//
#include <hip/hip_runtime.h>
#include <hip/hip_bf16.h>

typedef __bf16 bf16x8 __attribute__((ext_vector_type(8)));
typedef __bf16 bf16x4 __attribute__((ext_vector_type(4)));
typedef float  f32x4  __attribute__((ext_vector_type(4)));

#define MFMA(a, b, c) __builtin_amdgcn_mfma_f32_16x16x32_bf16((a), (b), (c), 0, 0, 0)

#define GLOAD16(gp, lp) __builtin_amdgcn_global_load_lds(                      \
    (const __attribute__((address_space(1))) void*)(gp),                       \
    (__attribute__((address_space(3))) void*)(lp), 16, 0, 0)

__device__ inline unsigned int pkbf(float a, float b) {
    __bf16 x = (__bf16)a, y = (__bf16)b;
    return (unsigned int)*(unsigned short*)&x |
           ((unsigned int)*(unsigned short*)&y << 16);
}

// ---------------------------------------------------------------------------
// Weight transpose + f32->bf16 convert:  src f32 [K][N]  ->  dst bf16 [N][K]
// ---------------------------------------------------------------------------
__global__ __launch_bounds__(256) void transpose_cvt(
    const float* __restrict__ src, __bf16* __restrict__ dst, int Kd, int Nd)
{
    __shared__ float tile[32][33];
    const int k0 = blockIdx.y * 32, n0 = blockIdx.x * 32;
    const int t = threadIdx.x;
    const int r = t >> 5, c = t & 31;
#pragma unroll
    for (int i = 0; i < 4; ++i)
        tile[r + i * 8][c] = src[(long)(k0 + r + i * 8) * Nd + n0 + c];
    __syncthreads();
#pragma unroll
    for (int i = 0; i < 4; ++i)
        dst[(long)(n0 + r + i * 8) * Kd + k0 + c] = (__bf16)tile[c][r + i * 8];
}

// V [bh][2048][64] -> Vt [bh][64][2048]   (bf16 tiled transpose)
__global__ __launch_bounds__(256) void transpose_v(
    const __bf16* __restrict__ V, __bf16* __restrict__ Vt)
{
    __shared__ __bf16 tile[32][33];
    const int bh = blockIdx.z;
    const int s0 = blockIdx.x * 32, d0 = blockIdx.y * 32;
    const int t = threadIdx.x, r = t >> 5, c = t & 31;
    const __bf16* Vp = V + (long)bh * 2048 * 64;
    __bf16* Tp = Vt + (long)bh * 64 * 2048;
#pragma unroll
    for (int i = 0; i < 4; ++i)
        tile[r + i * 8][c] = Vp[(long)(s0 + r + i * 8) * 64 + d0 + c];
    __syncthreads();
#pragma unroll
    for (int i = 0; i < 4; ++i)
        Tp[(long)(d0 + r + i * 8) * 2048 + s0 + c] = tile[c][r + i * 8];
}

// ---------------------------------------------------------------------------
// LayerNorm (torch: ddof=1 std, eps added to std), f32 in, bf16 out
// ---------------------------------------------------------------------------
__global__ __launch_bounds__(256) void ln_kernel(
    const float* __restrict__ in, const float* __restrict__ ga,
    const float* __restrict__ gb, __bf16* __restrict__ out)
{
    const int row = blockIdx.x;
    const int t = threadIdx.x;
    const float4 xv = *(const float4*)(in + (long)row * 1024 + t * 4);
    float s  = xv.x + xv.y + xv.z + xv.w;
    float sq = xv.x * xv.x + xv.y * xv.y + xv.z * xv.z + xv.w * xv.w;
#pragma unroll
    for (int off = 32; off; off >>= 1) {
        s  += __shfl_xor(s, off);
        sq += __shfl_xor(sq, off);
    }
    __shared__ float red[8];
    const int w = t >> 6;
    if ((t & 63) == 0) { red[w * 2] = s; red[w * 2 + 1] = sq; }
    __syncthreads();
    s  = red[0] + red[2] + red[4] + red[6];
    sq = red[1] + red[3] + red[5] + red[7];
    const float mean = s * (1.0f / 1024.0f);
    const float var  = fmaxf((sq - s * mean) * (1.0f / 1023.0f), 0.0f);
    const float dinv = 1.0f / (sqrtf(var) + 1e-6f);
    const float4 av = *(const float4*)(ga + t * 4);
    const float4 bv = *(const float4*)(gb + t * 4);
    bf16x4 o;
    o[0] = (__bf16)((xv.x - mean) * dinv * av.x + bv.x);
    o[1] = (__bf16)((xv.y - mean) * dinv * av.y + bv.y);
    o[2] = (__bf16)((xv.z - mean) * dinv * av.z + bv.z);
    o[3] = (__bf16)((xv.w - mean) * dinv * av.w + bv.w);
    *(bf16x4*)(out + (long)row * 1024 + t * 4) = o;
}

// ---------------------------------------------------------------------------
// GEMM: C[M,N] = A[M,K] @ Bt^T, 128x128 tile, BK=32, global_load_lds staging.
// ---------------------------------------------------------------------------
template <int MODE>
__global__ __launch_bounds__(256) void gemm_bt(
    const __bf16* __restrict__ A, const __bf16* __restrict__ Bt,
    int M, int N, int K,
    const float* __restrict__ bias, const float* resid,
    float* outf, __bf16* __restrict__ outb,
    __bf16* __restrict__ qb, __bf16* __restrict__ kb, __bf16* __restrict__ vb)
{
    __shared__ __align__(16) __bf16 Alds[128 * 32];
    __shared__ __align__(16) __bf16 Blds[128 * 32];

    const int t = threadIdx.x;
    const int lane = t & 63, w = t >> 6;
    const int wr = w >> 1, wc = w & 1;
    const int g = lane >> 4, l15 = lane & 15;
    const int bm = blockIdx.y * 128, bn = blockIdx.x * 128;

    const int cr = t >> 2;                 // chunk row 0..63
    const int cc = (t & 3) * 8;            // elem col
    const __bf16* Ag  = A  + (long)(bm + cr) * K + cc;
    const __bf16* Ag2 = Ag + (long)64 * K;
    const __bf16* Bg  = Bt + (long)(bn + cr) * K + cc;
    const __bf16* Bg2 = Bg + (long)64 * K;
    char* Alp = (char*)Alds + t * 16;
    char* Blp = (char*)Blds + t * 16;

    f32x4 acc[4][4] = {};
    const int nk = K / 32;

    for (int kt = 0; kt < nk; ++kt) {
        const long ko = (long)kt * 32;
        __syncthreads();
        GLOAD16(Ag + ko,  Alp);
        GLOAD16(Ag2 + ko, Alp + 4096);
        GLOAD16(Bg + ko,  Blp);
        GLOAD16(Bg2 + ko, Blp + 4096);
        __syncthreads();
        bf16x8 af[4], bfr[4];
#pragma unroll
        for (int mi = 0; mi < 4; ++mi)
            af[mi] = *(const bf16x8*)(Alds + (wr * 64 + mi * 16 + l15) * 32 + g * 8);
#pragma unroll
        for (int ni = 0; ni < 4; ++ni)
            bfr[ni] = *(const bf16x8*)(Blds + (wc * 64 + ni * 16 + l15) * 32 + g * 8);
#pragma unroll
        for (int mi = 0; mi < 4; ++mi)
#pragma unroll
            for (int ni = 0; ni < 4; ++ni)
                acc[mi][ni] = MFMA(af[mi], bfr[ni], acc[mi][ni]);
    }

    // C/D layout: col = lane&15, row = (lane>>4)*4 + reg
#pragma unroll
    for (int mi = 0; mi < 4; ++mi) {
#pragma unroll
        for (int ni = 0; ni < 4; ++ni) {
#pragma unroll
            for (int r = 0; r < 4; ++r) {
                const int gr = bm + wr * 64 + mi * 16 + g * 4 + r;
                const int gc = bn + wc * 64 + ni * 16 + l15;
                const float vacc = acc[mi][ni][r];
                if constexpr (MODE == 0) {
                    const int bufi = gc >> 10;
                    const int hd = gc & 1023;
                    const int h = hd >> 6, d = hd & 63;
                    const int b = gr >> 11, sx = gr & 2047;
                    __bf16* dst = (bufi == 0) ? qb : ((bufi == 1) ? kb : vb);
                    dst[((long)((b * 16 + h) * 2048 + sx)) * 64 + d] = (__bf16)vacc;
                } else if constexpr (MODE == 1) {
                    const long idx = (long)gr * N + gc;
                    outf[idx] = vacc + resid[idx];
                } else if constexpr (MODE == 2) {
                    const float y = fmaxf(vacc + bias[gc], 0.0f);
                    outb[(long)gr * N + gc] = (__bf16)y;
                } else {
                    const long idx = (long)gr * N + gc;
                    outf[idx] = vacc + bias[gc] + resid[idx];
                }
            }
        }
    }
}

// ---------------------------------------------------------------------------
// Flash attention. Per block: 128 q rows (4 waves x 2 q-frags), KVBLK=64.
// Swapped QK^T: S^T frag rows = kv, cols = q. P repacked to contiguous
// k-mapping via shuffles; PV uses Vt (V^T) with b128 swizzled LDS reads.
// LDS tiles are [64 rows][128B]; swizzle byte ^= (row&7)<<4 (both sides).
// ---------------------------------------------------------------------------
__global__ __launch_bounds__(256, 2) void attn_kernel(
    const __bf16* __restrict__ Q, const __bf16* __restrict__ Kk,
    const __bf16* __restrict__ Vt, const int* __restrict__ mask,
    __bf16* __restrict__ O)
{
    __shared__ __align__(16) char Klds[8192];
    __shared__ __align__(16) char Vlds[8192];
    __shared__ int mlds[64];

    const int t = threadIdx.x;
    const int lane = t & 63, w = t >> 6;
    const int g = lane >> 4, l15 = lane & 15;
    const int bh = blockIdx.x >> 4;
    const int qt = blockIdx.x & 15;
    const int b = bh >> 4, h = bh & 15;
    const int q0 = qt * 128 + w * 32;

    const __bf16* Qp = Q  + (long)bh * 2048 * 64;
    const __bf16* Kp = Kk + (long)bh * 2048 * 64;
    const __bf16* Vp = Vt + (long)bh * 64 * 2048;
    const int* mp = mask + b * 2048;

    bf16x8 qreg[2][2];
#pragma unroll
    for (int qf = 0; qf < 2; ++qf)
#pragma unroll
        for (int kh = 0; kh < 2; ++kh)
            qreg[qf][kh] = *(const bf16x8*)(Qp + (long)(q0 + qf * 16 + l15) * 64 + kh * 32 + g * 8);

    float m_run[2] = {-1e30f, -1e30f}, l_run[2] = {0.0f, 0.0f};
    f32x4 ot[2][4] = {};

    // staging: thread t handles 16B chunks c=t (rows 0..31) and c=t+256 (rows 32..63)
    const int sr0 = t >> 3;                  // 0..31
    const int sce = (t & 7) * 8;             // elem col
    const int swz0 = sr0 * 128 + (((t & 7) * 16) ^ ((sr0 & 7) << 4));
    const int swz1 = swz0 + 32 * 128;

    bf16x8 kr0 = *(const bf16x8*)(Kp + (long)sr0 * 64 + sce);
    bf16x8 kr1 = *(const bf16x8*)(Kp + (long)(sr0 + 32) * 64 + sce);
    bf16x8 vr0 = *(const bf16x8*)(Vp + (long)sr0 * 2048 + sce);
    bf16x8 vr1 = *(const bf16x8*)(Vp + (long)(sr0 + 32) * 2048 + sce);
    int mr = (t < 64) ? mp[t] : 0;

    for (int kc = 0; kc < 32; ++kc) {
        __syncthreads();
        *(bf16x8*)(Klds + swz0) = kr0;
        *(bf16x8*)(Klds + swz1) = kr1;
        *(bf16x8*)(Vlds + swz0) = vr0;
        *(bf16x8*)(Vlds + swz1) = vr1;
        if (t < 64) mlds[t] = mr;
        __syncthreads();
        if (kc < 31) {
            const int kv0 = (kc + 1) * 64;
            kr0 = *(const bf16x8*)(Kp + (long)(kv0 + sr0) * 64 + sce);
            kr1 = *(const bf16x8*)(Kp + (long)(kv0 + sr0 + 32) * 64 + sce);
            vr0 = *(const bf16x8*)(Vp + (long)sr0 * 2048 + kv0 + sce);
            vr1 = *(const bf16x8*)(Vp + (long)(sr0 + 32) * 2048 + kv0 + sce);
            if (t < 64) mr = mp[kv0 + t];
        }

        // ---- QK^T: kf[f][dh] = K rows f*16+l15, k = dh*32 + g*8..+7
        bf16x8 kf[4][2];
#pragma unroll
        for (int f = 0; f < 4; ++f)
#pragma unroll
            for (int dh = 0; dh < 2; ++dh)
                kf[f][dh] = *(const bf16x8*)(Klds + (f * 16 + l15) * 128 +
                                             (((dh * 64 + g * 16)) ^ ((l15 & 7) << 4)));
        f32x4 sf[2][4] = {};
        __builtin_amdgcn_s_setprio(1);
#pragma unroll
        for (int qf = 0; qf < 2; ++qf)
#pragma unroll
            for (int f = 0; f < 4; ++f) {
                sf[qf][f] = MFMA(kf[f][0], qreg[qf][0], sf[qf][f]);
                sf[qf][f] = MFMA(kf[f][1], qreg[qf][1], sf[qf][f]);
            }
        __builtin_amdgcn_s_setprio(0);

        int mvv[16];
#pragma unroll
        for (int f = 0; f < 4; ++f) {
            const int4 mq = *(const int4*)&mlds[f * 16 + g * 4];
            mvv[f * 4 + 0] = mq.x; mvv[f * 4 + 1] = mq.y;
            mvv[f * 4 + 2] = mq.z; mvv[f * 4 + 3] = mq.w;
        }

        // V^T fragments (shared across q-frags): rows d = df*16+l15, k = kv
        bf16x8 av[4][2];
#pragma unroll
        for (int df = 0; df < 4; ++df)
#pragma unroll
            for (int hh = 0; hh < 2; ++hh)
                av[df][hh] = *(const bf16x8*)(Vlds + (df * 16 + l15) * 128 +
                                              (((hh * 64 + g * 16)) ^ ((l15 & 7) << 4)));

#pragma unroll
        for (int qf = 0; qf < 2; ++qf) {
            float s[16], p[16];
            float mx = -1e30f;
#pragma unroll
            for (int i = 0; i < 16; ++i) {
                float xs = sf[qf][i >> 2][i & 3] * 0.125f;
                if (mvv[i] == 0) xs = -1e9f;
                s[i] = xs;
                mx = fmaxf(mx, xs);
            }
            mx = fmaxf(mx, __shfl_xor(mx, 16));
            mx = fmaxf(mx, __shfl_xor(mx, 32));
            const float m_new = fmaxf(m_run[qf], mx);
            const float alpha = __expf(m_run[qf] - m_new);
            float ps = 0.0f;
#pragma unroll
            for (int i = 0; i < 16; ++i) { p[i] = __expf(s[i] - m_new); ps += p[i]; }
            ps += __shfl_xor(ps, 16);
            ps += __shfl_xor(ps, 32);
            l_run[qf] = l_run[qf] * alpha + ps;
            m_run[qf] = m_new;
#pragma unroll
            for (int df = 0; df < 4; ++df)
#pragma unroll
                for (int r = 0; r < 4; ++r) ot[qf][df][r] *= alpha;

            // repack halves to contiguous kv = g*8+j, then PV
#pragma unroll
            for (int hh = 0; hh < 2; ++hh) {
                // lane (g,l15) owns kv: u0,u1 -> hh*32+g*4+{0..3}; u2,u3 -> hh*32+16+g*4+{0..3}
                unsigned int u0 = pkbf(p[hh * 8 + 0], p[hh * 8 + 1]);
                unsigned int u1 = pkbf(p[hh * 8 + 2], p[hh * 8 + 3]);
                unsigned int u2 = pkbf(p[hh * 8 + 4], p[hh * 8 + 5]);
                unsigned int u3 = pkbf(p[hh * 8 + 6], p[hh * 8 + 7]);
                const unsigned int a0 = __shfl_xor(u0, 16), a1 = __shfl_xor(u1, 16);
                const unsigned int b0 = __shfl_xor(u2, 16), b1 = __shfl_xor(u3, 16);
                const bool ge = ((g & 1) == 0);
                // E = kv hh*32 + (g>>1)*8 + 0..7 ; F = same + 16
                const unsigned int E0 = ge ? u0 : a0, E1 = ge ? u1 : a1;
                const unsigned int E2 = ge ? a0 : u0, E3 = ge ? a1 : u1;
                const unsigned int F0 = ge ? u2 : b0, F1 = ge ? u3 : b1;
                const unsigned int F2 = ge ? b0 : u2, F3 = ge ? b1 : u3;
                // g0 sends F (to g2), g3 sends E (to g1)
                const unsigned int S0 = (g < 2) ? F0 : E0, S1 = (g < 2) ? F1 : E1;
                const unsigned int S2 = (g < 2) ? F2 : E2, S3 = (g < 2) ? F3 : E3;
                const unsigned int R0 = __shfl_xor(S0, 32), R1 = __shfl_xor(S1, 32);
                const unsigned int R2 = __shfl_xor(S2, 32), R3 = __shfl_xor(S3, 32);
                unsigned int P0 = (g == 0) ? E0 : (g == 3) ? F0 : R0;
                unsigned int P1 = (g == 0) ? E1 : (g == 3) ? F1 : R1;
                unsigned int P2 = (g == 0) ? E2 : (g == 3) ? F2 : R2;
                unsigned int P3 = (g == 0) ? E3 : (g == 3) ? F3 : R3;
                unsigned int pu[4] = {P0, P1, P2, P3};
                bf16x8 pf = *(bf16x8*)pu;   // elem j = P[q=l15][kv = hh*32+g*8+j]
                __builtin_amdgcn_s_setprio(1);
#pragma unroll
                for (int df = 0; df < 4; ++df)
                    ot[qf][df] = MFMA(av[df][hh], pf, ot[qf][df]);
                __builtin_amdgcn_s_setprio(0);
            }
        }
    }

    // epilogue: ot[qf][df][r] = O^T[d = df*16+g*4+r][q = q0+qf*16+l15]
#pragma unroll
    for (int qf = 0; qf < 2; ++qf) {
        const float inv = 1.0f / l_run[qf];
        const int q = q0 + qf * 16 + l15;
        __bf16* orow = O + (long)(b * 2048 + q) * 1024 + h * 64;
#pragma unroll
        for (int df = 0; df < 4; ++df)
#pragma unroll
            for (int rp = 0; rp < 2; ++rp) {
                const int d = df * 16 + g * 4 + rp * 2;
                *(unsigned int*)(orow + d) =
                    pkbf(ot[qf][df][rp * 2] * inv, ot[qf][df][rp * 2 + 1] * inv);
            }
    }
}

// ---------------------------------------------------------------------------
extern "C" void kernel_launch(void* const* d_in, const int* in_sizes, int n_in,
                              void* d_out, int out_size, void* d_ws, size_t ws_size,
                              hipStream_t stream)
{
    const float* x    = (const float*)d_in[0];
    const int*   mask = (const int*)  d_in[1];
    const float* wq   = (const float*)d_in[2];
    const float* wk   = (const float*)d_in[3];
    const float* wv   = (const float*)d_in[4];
    const float* wo   = (const float*)d_in[5];
    const float* w1   = (const float*)d_in[6];
    const float* b1   = (const float*)d_in[7];
    const float* w2   = (const float*)d_in[8];
    const float* b2   = (const float*)d_in[9];
    const float* l1a  = (const float*)d_in[10];
    const float* l1b  = (const float*)d_in[11];
    const float* l2a  = (const float*)d_in[12];
    const float* l2b  = (const float*)d_in[13];
    float* out = (float*)d_out;

    char* ws = (char*)d_ws;
    __bf16* wqkvT = (__bf16*)(ws);                       // [3072][1024]  6 MB
    __bf16* woT   = (__bf16*)(ws + 6291456);             // [1024][1024]  2 MB
    __bf16* w1T   = (__bf16*)(ws + 8388608);             // [4096][1024]  8 MB
    __bf16* w2T   = (__bf16*)(ws + 16777216);            // [1024][4096]  8 MB
    __bf16* xn    = (__bf16*)(ws + 25165824);            // [8192][1024] 16 MB (doubles as Vt)
    __bf16* Vtb   = (__bf16*)(ws + 25165824);            // [64][64][2048] 16 MB (after QKV gemm)
    __bf16* Qb    = (__bf16*)(ws + 41943040);            // [64][2048][64] 16 MB
    __bf16* Kb    = (__bf16*)(ws + 58720256);            // 16 MB
    __bf16* Vb    = (__bf16*)(ws + 75497472);            // 16 MB
    __bf16* attO  = (__bf16*)(ws + 92274688);            // [8192][1024] 16 MB
    __bf16* ffh   = (__bf16*)(ws + 41943040);            // [8192][4096] 64 MB (reuses Qb..attO)

    transpose_cvt<<<dim3(32, 32),  256, 0, stream>>>(wq, wqkvT,               1024, 1024);
    transpose_cvt<<<dim3(32, 32),  256, 0, stream>>>(wk, wqkvT + 1024 * 1024, 1024, 1024);
    transpose_cvt<<<dim3(32, 32),  256, 0, stream>>>(wv, wqkvT + 2048 * 1024, 1024, 1024);
    transpose_cvt<<<dim3(32, 32),  256, 0, stream>>>(wo, woT,                 1024, 1024);
    transpose_cvt<<<dim3(128, 32), 256, 0, stream>>>(w1, w1T,                 1024, 4096);
    transpose_cvt<<<dim3(32, 128), 256, 0, stream>>>(w2, w2T,                 4096, 1024);

    ln_kernel<<<8192, 256, 0, stream>>>(x, l1a, l1b, xn);
    gemm_bt<0><<<dim3(24, 64), 256, 0, stream>>>(xn, wqkvT, 8192, 3072, 1024,
                                                 nullptr, nullptr, nullptr, nullptr, Qb, Kb, Vb);
    transpose_v<<<dim3(64, 2, 64), 256, 0, stream>>>(Vb, Vtb);
    attn_kernel<<<1024, 256, 0, stream>>>(Qb, Kb, Vtb, mask, attO);
    gemm_bt<1><<<dim3(8, 64), 256, 0, stream>>>(attO, woT, 8192, 1024, 1024,
                                                nullptr, x, out, nullptr, nullptr, nullptr, nullptr);
    ln_kernel<<<8192, 256, 0, stream>>>(out, l2a, l2b, xn);
    gemm_bt<2><<<dim3(32, 64), 256, 0, stream>>>(xn, w1T, 8192, 4096, 1024,
                                                 b1, nullptr, nullptr, ffh, nullptr, nullptr, nullptr);
    gemm_bt<3><<<dim3(8, 64), 256, 0, stream>>>(ffh, w2T, 8192, 1024, 4096,
                                                b2, out, out, nullptr, nullptr, nullptr, nullptr);
    (void)in_sizes; (void)n_in; (void)out_size; (void)ws_size;
}